// Round 1
// baseline (112.782 us; speedup 1.0000x reference)
//
#include <hip/hip_runtime.h>

// Problem constants
#define DD 20          // hypervol spatial extent per axis
#define MM 32          // channel count m
#define OO 19          // output extent per axis (DD - RANK + 1, RANK=2)
#define NBLK (OO*OO*OO)

// workspace layout (floats):
//   Ct[19][32][32]  transposed cosine table: Ct[k][j][i] = cos(2*pi*k/(i*32+j+2))
//   Pt[32][32]      P transposed:  Pt[j][i] = P[i][j]
//   Mt[32][32]      M_w transposed: Mt[j][i] = M_w[i][j]
#define CT_FLOATS (OO*MM*MM)         // 19456
#define PT_OFF CT_FLOATS             // 19456
#define MT_OFF (PT_OFF + MM*MM)      // 20480
#define WS_FLOATS (MT_OFF + MM*MM)   // 21504

__global__ __launch_bounds__(256) void build_tables_kernel(
        const float* __restrict__ Mw, const float* __restrict__ P,
        float* __restrict__ ws) {
    int idx = blockIdx.x * 256 + threadIdx.x;
    if (idx < CT_FLOATS) {
        int k = idx >> 10;        // axis position 0..18
        int r = idx & 1023;
        int j = r >> 5;           // transposed: slow index is j
        int i = r & 31;
        float period = (float)(i * MM + j + 2);
        ws[idx] = cosf(6.28318530717958647692f * (float)k / period);
    } else if (idx < MT_OFF) {
        int r = idx - PT_OFF;
        ws[idx] = P[(r & 31) * MM + (r >> 5)];     // Pt[j][i] = P[i][j]
    } else if (idx < WS_FLOATS) {
        int r = idx - MT_OFF;
        ws[idx] = Mw[(r & 31) * MM + (r >> 5)];    // Mt[j][i] = Mw[i][j]
    }
}

// One block per (a,b,c); 256 threads = (g = tid>>5 in 0..7, i = tid&31).
// Each g-group owns d in {g, g+8, g+16}.
__global__ __launch_bounds__(256) void spatial_kernel(
        const float* __restrict__ H, const float* __restrict__ ws,
        float* __restrict__ out) {
    __shared__ float sS[DD * MM];      // window pre-sums over (a..a+1,b..b+1,c..c+1)
    __shared__ float sMt[MM * MM];     // Mt staged
    __shared__ float sQPt[MM * MM];    // P .* Ct[a] .* Ct[b] .* Ct[c]  ([j][i])
    __shared__ float sX[OO * MM];      // x[d][i] = (win[d] @ M^T)_i

    const int tid = threadIdx.x;
    const int i = tid & 31;
    const int g = tid >> 5;

    const int blk = blockIdx.x;
    const int c = blk % OO;
    const int b = (blk / OO) % OO;
    const int a = blk / (OO * OO);

    const float* __restrict__ Ct = ws;
    const float* __restrict__ Pt = ws + PT_OFF;
    const float* __restrict__ Mt = ws + MT_OFF;

    // stage Mt (256 x float4 = 1024 floats), coalesced
    ((float4*)sMt)[tid] = ((const float4*)Mt)[tid];

    // build QPt = Pt .* Ct[a] .* Ct[b] .* Ct[c]   (all coalesced float4)
    {
        float4 p  = ((const float4*)Pt)[tid];
        float4 xa = ((const float4*)(Ct + a * (MM*MM)))[tid];
        float4 xb = ((const float4*)(Ct + b * (MM*MM)))[tid];
        float4 xc = ((const float4*)(Ct + c * (MM*MM)))[tid];
        float4 q;
        q.x = p.x * xa.x * xb.x * xc.x;
        q.y = p.y * xa.y * xb.y * xc.y;
        q.z = p.z * xa.z * xb.z * xc.z;
        q.w = p.w * xa.w * xb.w * xc.w;
        ((float4*)sQPt)[tid] = q;
    }

    // pre-sum 8 spatial shifts (a/b/c axes) for every d; lane-i coalesced 128B
    for (int d = g; d < DD; d += 8) {
        float s = 0.f;
        #pragma unroll
        for (int da = 0; da < 2; ++da)
            #pragma unroll
            for (int db = 0; db < 2; ++db)
                #pragma unroll
                for (int dc = 0; dc < 2; ++dc) {
                    int base = (((a + da) * DD + (b + db)) * DD + (c + dc)) * DD + d;
                    s += H[base * MM + i];
                }
        sS[d * MM + i] = s;
    }
    __syncthreads();

    // x[d][i] = sum_j win[d][j] * Mw[i][j];  win = (S[d]+S[d+1])/16
    // sS reads broadcast (uniform per half-wave); sMt reads lane-consecutive.
    for (int d = g; d < OO; d += 8) {
        float acc = 0.f;
        #pragma unroll
        for (int j = 0; j < MM; ++j) {
            float wj = (sS[d * MM + j] + sS[(d + 1) * MM + j]) * 0.0625f;
            acc += wj * sMt[j * MM + i];
        }
        sX[d * MM + i] = acc;
    }
    __syncthreads();

    // out[d][i] = sum_j x[d][j] * QPt[j][i] * Ct[d][j][i]
    for (int d = g; d < OO; d += 8) {
        // hoist x row into registers (broadcast b128 reads)
        float xr[MM];
        #pragma unroll
        for (int jj = 0; jj < MM / 4; ++jj) {
            float4 v = ((const float4*)(sX + d * MM))[jj];
            xr[jj*4+0] = v.x; xr[jj*4+1] = v.y; xr[jj*4+2] = v.z; xr[jj*4+3] = v.w;
        }
        const float* __restrict__ ctd = Ct + d * (MM*MM) + i;   // lane-coalesced
        float acc = 0.f;
        #pragma unroll
        for (int j = 0; j < MM; ++j) {
            acc += xr[j] * sQPt[j * MM + i] * ctd[j * MM];
        }
        out[(blk * OO + d) * MM + i] = acc;
    }
}

extern "C" void kernel_launch(void* const* d_in, const int* in_sizes, int n_in,
                              void* d_out, int out_size, void* d_ws, size_t ws_size,
                              hipStream_t stream) {
    const float* H  = (const float*)d_in[0];   // hypervol [20,20,20,20,32]
    const float* Mw = (const float*)d_in[1];   // M_w [32,32]
    const float* P  = (const float*)d_in[2];   // P   [32,32]
    float* out = (float*)d_out;
    float* ws  = (float*)d_ws;

    const int tblocks = (WS_FLOATS + 255) / 256;  // 84
    build_tables_kernel<<<tblocks, 256, 0, stream>>>(Mw, P, ws);
    spatial_kernel<<<NBLK, 256, 0, stream>>>(H, ws, out);
}